// Round 3
// baseline (279.222 us; speedup 1.0000x reference)
//
#include <hip/hip_runtime.h>

#define TMAX 64

__global__ __launch_bounds__(256, 4) void snn_fused(
    const float* __restrict__ x,       // [B,1,10,10]
    const float* __restrict__ conv_w,  // [2,1,4,4]
    const float* __restrict__ conv_b,  // [2]
    const float* __restrict__ fc_w,    // [10,72]
    const float* __restrict__ fc_b,    // [10]
    const int*   __restrict__ nsteps,  // scalar
    float*       __restrict__ out,     // [B,10]
    int B)
{
    __shared__ double d_F[TMAX];       // F(m) = 0.9^m - 0.8^m  (double)
    __shared__ float  s_r[TMAX];       // r_s = G(T-1-s)
    __shared__ float  s_tab[8][256];   // byte tables: sum of r over set bits
    __shared__ float  s_fcw[720];
    __shared__ float  s_fcb[16];
    __shared__ float  s_cb;            // C_b = sum_{m<T} F(m)

    const int tid = threadIdx.x;
    int T = nsteps[0];
    if (T > TMAX) T = TMAX;
    if (T < 0) T = 0;

    // --- setup: F(m) in double ---
    if (tid < TMAX) {
        double p9 = 1.0, p8 = 1.0;
        for (int k = 0; k < tid; ++k) { p9 *= 0.9; p8 *= 0.8; }
        d_F[tid] = p9 - p8;
    }
    for (int idx = tid; idx < 720; idx += 256) s_fcw[idx] = fc_w[idx];
    if (tid < 10) s_fcb[tid] = fc_b[tid];
    __syncthreads();

    // --- r_s = G(T-1-s), double accumulate ---
    if (tid < TMAX) {
        double r = 0.0;
        if (tid < T) {
            const int n = T - 1 - tid;
            for (int u = 0; u <= n; ++u) r += d_F[n - u] * d_F[u];
        }
        s_r[tid] = (float)r;
    }
    if (tid == 0) {
        double cb = 0.0;
        for (int m = 0; m < T; ++m) cb += d_F[m];
        s_cb = (float)cb;
    }
    __syncthreads();

    // --- byte lookup tables ---
    {
        const int v8 = tid; // 0..255
        #pragma unroll
        for (int k = 0; k < 8; ++k) {
            float ssum = 0.f;
            #pragma unroll
            for (int bb = 0; bb < 8; ++bb)
                if ((v8 >> bb) & 1) ssum += s_r[k * 8 + bb];
            s_tab[k][v8] = ssum;
        }
    }
    __syncthreads();

    const float cbsum = s_cb;

    const int gt = blockIdx.x * 256 + tid;
    const int b = gt >> 1;
    const int c = gt & 1;
    if (b >= B) return;

    const float* xb = x + b * 100;

    float wc[16];
    {
        const float4* wq = reinterpret_cast<const float4*>(conv_w + c * 16);
        #pragma unroll
        for (int k = 0; k < 4; ++k) {
            float4 t = wq[k];
            wc[4*k+0] = t.x; wc[4*k+1] = t.y; wc[4*k+2] = t.z; wc[4*k+3] = t.w;
        }
    }
    const float cbias = conv_b[c];

    // ---- Phase A: conv -> gg[49], streaming one x-row at a time ----
    // Accumulation order per output element is exactly (ky asc, kx asc), then +bias:
    // identical fp32 sequence to the passing round-2 kernel.
    float gg[49];
    #pragma unroll
    for (int e = 0; e < 49; ++e) gg[e] = 0.f;

    #pragma unroll
    for (int rr = 0; rr < 10; ++rr) {
        float xrow[10];
        const float2* q = reinterpret_cast<const float2*>(xb + rr * 10);
        #pragma unroll
        for (int k = 0; k < 5; ++k) { float2 t = q[k]; xrow[2*k] = t.x; xrow[2*k+1] = t.y; }
        const int ylo = (rr >= 3) ? (rr - 3) : 0;
        const int yhi = (rr <= 6) ? rr : 6;
        #pragma unroll
        for (int y = ylo; y <= yhi; ++y) {
            const int ky = rr - y;
            #pragma unroll
            for (int xx = 0; xx < 7; ++xx) {
                float a = gg[y*7 + xx];
                #pragma unroll
                for (int kx = 0; kx < 4; ++kx)
                    a = __fadd_rn(a, __fmul_rn(wc[ky*4 + kx], xrow[xx + kx]));
                gg[y*7 + xx] = a;
            }
        }
    }
    #pragma unroll
    for (int e = 0; e < 49; ++e) gg[e] = __fadd_rn(gg[e], cbias);

    // ---- Phase B: LIF rows + pool + temporal LUT + FC accumulate ----
    float outacc[10];
    #pragma unroll
    for (int o = 0; o < 10; ++o) outacc[o] = 0.f;

    unsigned int plo[7], phi[7];

    const int tlo = T < 32 ? T : 32;
    const int thi = T > 32 ? (T - 32) : 0;

    #pragma unroll
    for (int y = 0; y < 7; ++y) {
        float v[7], ii[7];
        unsigned int mlo[7], mhi[7];
        #pragma unroll
        for (int xx = 0; xx < 7; ++xx) { v[xx] = 0.f; ii[xx] = 0.f; mlo[xx] = 0u; mhi[xx] = 0u; }

        for (int t = 0; t < tlo; ++t) {
            const unsigned int bit = 1u << t;
            #pragma unroll
            for (int xx = 0; xx < 7; ++xx) {
                const float imv  = __fsub_rn(ii[xx], v[xx]);
                const float vdec = __fadd_rn(v[xx], __fmul_rn(0.1f, imv));
                const float idec = __fsub_rn(ii[xx], __fmul_rn(0.2f, ii[xx]));
                const bool  sp   = vdec > 1.0f;
                v[xx]  = sp ? 0.f : vdec;
                ii[xx] = __fadd_rn(idec, gg[y*7 + xx]);
                if (sp) mlo[xx] |= bit;
            }
        }
        for (int t = 0; t < thi; ++t) {
            const unsigned int bit = 1u << t;
            #pragma unroll
            for (int xx = 0; xx < 7; ++xx) {
                const float imv  = __fsub_rn(ii[xx], v[xx]);
                const float vdec = __fadd_rn(v[xx], __fmul_rn(0.1f, imv));
                const float idec = __fsub_rn(ii[xx], __fmul_rn(0.2f, ii[xx]));
                const bool  sp   = vdec > 1.0f;
                v[xx]  = sp ? 0.f : vdec;
                ii[xx] = __fadd_rn(idec, gg[y*7 + xx]);
                if (sp) mhi[xx] |= bit;
            }
        }

        if (y > 0) {
            const int jbase = c * 36 + (y - 1) * 6;
            #pragma unroll
            for (int px = 0; px < 6; ++px) {
                const unsigned int pl = plo[px] | plo[px+1] | mlo[px] | mlo[px+1];
                const unsigned int ph = phi[px] | phi[px+1] | mhi[px] | mhi[px+1];
                float a = s_tab[0][pl & 255] + s_tab[1][(pl >> 8) & 255]
                        + s_tab[2][(pl >> 16) & 255] + s_tab[3][pl >> 24]
                        + s_tab[4][ph & 255] + s_tab[5][(ph >> 8) & 255]
                        + s_tab[6][(ph >> 16) & 255] + s_tab[7][ph >> 24];
                const int j = jbase + px;
                #pragma unroll
                for (int o = 0; o < 10; ++o)
                    outacc[o] = fmaf(s_fcw[o * 72 + j], a, outacc[o]);
            }
        }
        #pragma unroll
        for (int xx = 0; xx < 7; ++xx) { plo[xx] = mlo[xx]; phi[xx] = mhi[xx]; }
    }

    #pragma unroll
    for (int o = 0; o < 10; ++o) {
        float tot = outacc[o] + __shfl_xor(outacc[o], 1);
        tot = fmaf(cbsum, s_fcb[o], tot);
        if (c == 0) out[b * 10 + o] = tot;
    }
}

extern "C" void kernel_launch(void* const* d_in, const int* in_sizes, int n_in,
                              void* d_out, int out_size, void* d_ws, size_t ws_size,
                              hipStream_t stream) {
    const float* x      = (const float*)d_in[0];
    const float* conv_w = (const float*)d_in[1];
    const float* conv_b = (const float*)d_in[2];
    const float* fc_w   = (const float*)d_in[3];
    const float* fc_b   = (const float*)d_in[4];
    const int*   nsteps = (const int*)d_in[5];
    float* outp = (float*)d_out;

    const int B = in_sizes[0] / 100;
    const int total = 2 * B;
    const int block = 256;
    const int grid = (total + block - 1) / block;
    snn_fused<<<grid, block, 0, stream>>>(x, conv_w, conv_b, fc_w, fc_b, nsteps, outp, B);
}

// Round 4
// 96.449 us; speedup vs baseline: 2.8950x; 2.8950x over previous
//
#include <hip/hip_runtime.h>

#define TMAX 64

__global__ __launch_bounds__(256) void snn_fused(
    const float* __restrict__ x,       // [B,1,10,10]
    const float* __restrict__ conv_w,  // [2,1,4,4]
    const float* __restrict__ conv_b,  // [2]
    const float* __restrict__ fc_w,    // [10,72]
    const float* __restrict__ fc_b,    // [10]
    const int*   __restrict__ nsteps,  // scalar
    float*       __restrict__ out,     // [B,10]
    int B)
{
    __shared__ double d_F[TMAX];       // F(m) = 0.9^m - 0.8^m  (double)
    __shared__ float  s_r[TMAX];       // r_s = G(T-1-s)
    __shared__ float  s_tab[8][256];   // byte tables: sum of r over set bits
    __shared__ float  s_fcw[720];
    __shared__ float  s_fcb[16];
    __shared__ float  s_cb;            // C_b = sum_{m<T} F(m)

    const int tid = threadIdx.x;
    int T = nsteps[0];
    if (T > TMAX) T = TMAX;
    if (T < 0) T = 0;

    // --- setup: F(m) in double ---
    if (tid < TMAX) {
        double p9 = 1.0, p8 = 1.0;
        for (int k = 0; k < tid; ++k) { p9 *= 0.9; p8 *= 0.8; }
        d_F[tid] = p9 - p8;
    }
    for (int idx = tid; idx < 720; idx += 256) s_fcw[idx] = fc_w[idx];
    if (tid < 10) s_fcb[tid] = fc_b[tid];
    __syncthreads();

    // --- r_s = G(T-1-s), double accumulate ---
    if (tid < TMAX) {
        double r = 0.0;
        if (tid < T) {
            const int n = T - 1 - tid;
            for (int u = 0; u <= n; ++u) r += d_F[n - u] * d_F[u];
        }
        s_r[tid] = (float)r;
    }
    if (tid == 0) {
        double cb = 0.0;
        for (int m = 0; m < T; ++m) cb += d_F[m];
        s_cb = (float)cb;
    }
    __syncthreads();

    // --- byte lookup tables ---
    {
        const int v8 = tid; // 0..255
        #pragma unroll
        for (int k = 0; k < 8; ++k) {
            float ssum = 0.f;
            #pragma unroll
            for (int bb = 0; bb < 8; ++bb)
                if ((v8 >> bb) & 1) ssum += s_r[k * 8 + bb];
            s_tab[k][v8] = ssum;
        }
    }
    __syncthreads();

    const float cbsum = s_cb;

    const int gt = blockIdx.x * 256 + tid;
    const int b = gt >> 1;
    const int c = gt & 1;
    if (b >= B) return;

    const float* xb = x + b * 100;

    float wc[16];
    {
        const float4* wq = reinterpret_cast<const float4*>(conv_w + c * 16);
        #pragma unroll
        for (int k = 0; k < 4; ++k) {
            float4 t = wq[k];
            wc[4*k+0] = t.x; wc[4*k+1] = t.y; wc[4*k+2] = t.z; wc[4*k+3] = t.w;
        }
    }
    const float cbias = conv_b[c];

    float outacc[10];
    #pragma unroll
    for (int o = 0; o < 10; ++o) outacc[o] = 0.f;

    unsigned int plo[7], phi[7];
    #pragma unroll
    for (int xx = 0; xx < 7; ++xx) { plo[xx] = 0u; phi[xx] = 0u; }

    const int tlo = T < 32 ? T : 32;
    const int thi = T > 32 ? (T - 32) : 0;

    // ---- runtime y-loop: conv row (recomputed) + LIF + pool/LUT/FC ----
    for (int y = 0; y < 7; ++y) {
        // conv for row y: exact (ky asc, kx asc) sequential accumulation, then +bias
        float gg7[7];
        #pragma unroll
        for (int xx = 0; xx < 7; ++xx) gg7[xx] = 0.f;
        #pragma unroll
        for (int ky = 0; ky < 4; ++ky) {
            float xrow[10];
            const float2* q = reinterpret_cast<const float2*>(xb + (y + ky) * 10);
            #pragma unroll
            for (int k = 0; k < 5; ++k) { float2 t = q[k]; xrow[2*k] = t.x; xrow[2*k+1] = t.y; }
            #pragma unroll
            for (int xx = 0; xx < 7; ++xx) {
                float a = gg7[xx];
                #pragma unroll
                for (int kx = 0; kx < 4; ++kx)
                    a = __fadd_rn(a, __fmul_rn(wc[ky*4 + kx], xrow[xx + kx]));
                gg7[xx] = a;
            }
        }
        #pragma unroll
        for (int xx = 0; xx < 7; ++xx) gg7[xx] = __fadd_rn(gg7[xx], cbias);

        // LIF sim — exact reference fp32 arithmetic
        float v[7], ii[7];
        unsigned int mlo[7], mhi[7];
        #pragma unroll
        for (int xx = 0; xx < 7; ++xx) { v[xx] = 0.f; ii[xx] = 0.f; mlo[xx] = 0u; mhi[xx] = 0u; }

        #pragma unroll 4
        for (int t = 0; t < tlo; ++t) {
            const unsigned int bit = 1u << t;
            #pragma unroll
            for (int xx = 0; xx < 7; ++xx) {
                const float imv  = __fsub_rn(ii[xx], v[xx]);
                const float vdec = __fadd_rn(v[xx], __fmul_rn(0.1f, imv));
                const float idec = __fsub_rn(ii[xx], __fmul_rn(0.2f, ii[xx]));
                const bool  sp   = vdec > 1.0f;
                v[xx]  = sp ? 0.f : vdec;
                ii[xx] = __fadd_rn(idec, gg7[xx]);
                if (sp) mlo[xx] |= bit;
            }
        }
        #pragma unroll 4
        for (int t = 0; t < thi; ++t) {
            const unsigned int bit = 1u << t;
            #pragma unroll
            for (int xx = 0; xx < 7; ++xx) {
                const float imv  = __fsub_rn(ii[xx], v[xx]);
                const float vdec = __fadd_rn(v[xx], __fmul_rn(0.1f, imv));
                const float idec = __fsub_rn(ii[xx], __fmul_rn(0.2f, ii[xx]));
                const bool  sp   = vdec > 1.0f;
                v[xx]  = sp ? 0.f : vdec;
                ii[xx] = __fadd_rn(idec, gg7[xx]);
                if (sp) mhi[xx] |= bit;
            }
        }

        // pool (OR of 4 neighbor masks) + temporal weighting + FC accumulate
        if (y > 0) {
            const int jbase = c * 36 + (y - 1) * 6;
            #pragma unroll
            for (int px = 0; px < 6; ++px) {
                const unsigned int pl = plo[px] | plo[px+1] | mlo[px] | mlo[px+1];
                const unsigned int ph = phi[px] | phi[px+1] | mhi[px] | mhi[px+1];
                float a = s_tab[0][pl & 255] + s_tab[1][(pl >> 8) & 255]
                        + s_tab[2][(pl >> 16) & 255] + s_tab[3][pl >> 24]
                        + s_tab[4][ph & 255] + s_tab[5][(ph >> 8) & 255]
                        + s_tab[6][(ph >> 16) & 255] + s_tab[7][ph >> 24];
                const int j = jbase + px;
                #pragma unroll
                for (int o = 0; o < 10; ++o)
                    outacc[o] = fmaf(s_fcw[o * 72 + j], a, outacc[o]);
            }
        }
        #pragma unroll
        for (int xx = 0; xx < 7; ++xx) { plo[xx] = mlo[xx]; phi[xx] = mhi[xx]; }
    }

    #pragma unroll
    for (int o = 0; o < 10; ++o) {
        float tot = outacc[o] + __shfl_xor(outacc[o], 1);
        tot = fmaf(cbsum, s_fcb[o], tot);
        if (c == 0) out[b * 10 + o] = tot;
    }
}

extern "C" void kernel_launch(void* const* d_in, const int* in_sizes, int n_in,
                              void* d_out, int out_size, void* d_ws, size_t ws_size,
                              hipStream_t stream) {
    const float* x      = (const float*)d_in[0];
    const float* conv_w = (const float*)d_in[1];
    const float* conv_b = (const float*)d_in[2];
    const float* fc_w   = (const float*)d_in[3];
    const float* fc_b   = (const float*)d_in[4];
    const int*   nsteps = (const int*)d_in[5];
    float* outp = (float*)d_out;

    const int B = in_sizes[0] / 100;
    const int total = 2 * B;
    const int block = 256;
    const int grid = (total + block - 1) / block;
    snn_fused<<<grid, block, 0, stream>>>(x, conv_w, conv_b, fc_w, fc_b, nsteps, outp, B);
}

// Round 5
// 91.047 us; speedup vs baseline: 3.0668x; 1.0593x over previous
//
#include <hip/hip_runtime.h>

#define TMAX 64

__global__ __launch_bounds__(256) void snn_fused(
    const float* __restrict__ x,       // [B,1,10,10]
    const float* __restrict__ conv_w,  // [2,1,4,4]
    const float* __restrict__ conv_b,  // [2]
    const float* __restrict__ fc_w,    // [10,72]
    const float* __restrict__ fc_b,    // [10]
    const int*   __restrict__ nsteps,  // scalar
    float*       __restrict__ out,     // [B,10]
    int B)
{
    __shared__ double d_F[TMAX];       // F(m) = 0.9^m - 0.8^m  (double)
    __shared__ float  s_r[TMAX];       // r_s = G(T-1-s)  (time-indexed)
    __shared__ float  s_rb[TMAX];      // bit-position -> r  (addc bit order)
    __shared__ float  s_tab[8][256];   // byte tables over s_rb
    __shared__ float  s_fcw[720];
    __shared__ float  s_fcb[16];
    __shared__ float  s_cb;            // C_b = sum_{m<T} F(m)

    const int tid = threadIdx.x;
    int T = nsteps[0];
    if (T > TMAX) T = TMAX;
    if (T < 0) T = 0;
    const int tlo = T < 32 ? T : 32;
    const int thi = T > 32 ? (T - 32) : 0;

    // --- setup: F(m) in double ---
    if (tid < TMAX) {
        double p9 = 1.0, p8 = 1.0;
        for (int k = 0; k < tid; ++k) { p9 *= 0.9; p8 *= 0.8; }
        d_F[tid] = p9 - p8;
    }
    for (int idx = tid; idx < 720; idx += 256) s_fcw[idx] = fc_w[idx];
    if (tid < 10) s_fcb[tid] = fc_b[tid];
    __syncthreads();

    // --- r_s = G(T-1-s), double accumulate ---
    if (tid < TMAX) {
        double r = 0.0;
        if (tid < T) {
            const int n = T - 1 - tid;
            for (int u = 0; u <= n; ++u) r += d_F[n - u] * d_F[u];
        }
        s_r[tid] = (float)r;
    }
    if (tid == 0) {
        double cb = 0.0;
        for (int m = 0; m < T; ++m) cb += d_F[m];
        s_cb = (float)cb;
    }
    __syncthreads();

    // --- bit-position -> r map (m = 2m + sp ordering) ---
    // lo chunk: bit p corresponds to time t = tlo-1-p   (p < tlo)
    // hi chunk: bit p corresponds to time t = tlo+thi-1-p (p < thi)
    if (tid < 32) {
        s_rb[tid] = (tid < tlo) ? s_r[tlo - 1 - tid] : 0.f;
    } else if (tid < 64) {
        const int p = tid - 32;
        s_rb[tid] = (p < thi) ? s_r[tlo + thi - 1 - p] : 0.f;
    }
    __syncthreads();

    // --- byte lookup tables ---
    {
        const int v8 = tid; // 0..255
        #pragma unroll
        for (int k = 0; k < 8; ++k) {
            float ssum = 0.f;
            #pragma unroll
            for (int bb = 0; bb < 8; ++bb)
                if ((v8 >> bb) & 1) ssum += s_rb[k * 8 + bb];
            s_tab[k][v8] = ssum;
        }
    }
    __syncthreads();

    const float cbsum = s_cb;

    // lane mapping: h = row-half, c = channel, b = batch; 4 lanes per b
    const int gt = blockIdx.x * 256 + tid;
    const int h = gt & 1;
    const int c = (gt >> 1) & 1;
    const int b = gt >> 2;
    if (b >= B) return;

    const float* xb = x + b * 100;

    float wc[16];
    {
        const float4* wq = reinterpret_cast<const float4*>(conv_w + c * 16);
        #pragma unroll
        for (int k = 0; k < 4; ++k) {
            float4 t = wq[k];
            wc[4*k+0] = t.x; wc[4*k+1] = t.y; wc[4*k+2] = t.z; wc[4*k+3] = t.w;
        }
    }
    const float cbias = conv_b[c];

    float outacc[10];
    #pragma unroll
    for (int o = 0; o < 10; ++o) outacc[o] = 0.f;

    unsigned int plo[7], phi[7];
    float fzero = 0.0f;

    const int ybase = 3 * h;   // h=0: rows 0..3, h=1: rows 3..6 (row 3 duplicated)

    for (int r = 0; r < 4; ++r) {
        const int y = ybase + r;

        // conv for row y: exact (ky asc, kx asc) sequential accumulation, then +bias
        float gg7[7];
        #pragma unroll
        for (int xx = 0; xx < 7; ++xx) gg7[xx] = 0.f;
        #pragma unroll
        for (int ky = 0; ky < 4; ++ky) {
            float xrow[10];
            const float2* q = reinterpret_cast<const float2*>(xb + (y + ky) * 10);
            #pragma unroll
            for (int k = 0; k < 5; ++k) { float2 t = q[k]; xrow[2*k] = t.x; xrow[2*k+1] = t.y; }
            #pragma unroll
            for (int xx = 0; xx < 7; ++xx) {
                float a = gg7[xx];
                #pragma unroll
                for (int kx = 0; kx < 4; ++kx)
                    a = __fadd_rn(a, __fmul_rn(wc[ky*4 + kx], xrow[xx + kx]));
                gg7[xx] = a;
            }
        }
        #pragma unroll
        for (int xx = 0; xx < 7; ++xx) gg7[xx] = __fadd_rn(gg7[xx], cbias);

        // LIF sim — exact reference fp32 arithmetic; spike bits via m = 2m + sp
        float v[7], ii[7];
        unsigned int mlo[7], mhi[7];
        #pragma unroll
        for (int xx = 0; xx < 7; ++xx) { v[xx] = 0.f; ii[xx] = 0.f; mlo[xx] = 0u; mhi[xx] = 0u; }

        #pragma unroll 4
        for (int t = 0; t < tlo; ++t) {
            #pragma unroll
            for (int xx = 0; xx < 7; ++xx) {
                const float imv  = __fsub_rn(ii[xx], v[xx]);
                const float vdec = __fadd_rn(v[xx], __fmul_rn(0.1f, imv));
                const float idec = __fsub_rn(ii[xx], __fmul_rn(0.2f, ii[xx]));
                float vnew;
                asm("v_cmp_lt_f32 vcc, 1.0, %[vd]\n\t"
                    "v_cndmask_b32 %[vn], %[vd], %[vz], vcc\n\t"
                    "v_addc_co_u32 %[mm], vcc, %[mm], %[mm], vcc"
                    : [vn]"=v"(vnew), [mm]"+v"(mlo[xx])
                    : [vd]"v"(vdec), [vz]"v"(fzero)
                    : "vcc");
                v[xx]  = vnew;
                ii[xx] = __fadd_rn(idec, gg7[xx]);
            }
        }
        #pragma unroll 4
        for (int t = 0; t < thi; ++t) {
            #pragma unroll
            for (int xx = 0; xx < 7; ++xx) {
                const float imv  = __fsub_rn(ii[xx], v[xx]);
                const float vdec = __fadd_rn(v[xx], __fmul_rn(0.1f, imv));
                const float idec = __fsub_rn(ii[xx], __fmul_rn(0.2f, ii[xx]));
                float vnew;
                asm("v_cmp_lt_f32 vcc, 1.0, %[vd]\n\t"
                    "v_cndmask_b32 %[vn], %[vd], %[vz], vcc\n\t"
                    "v_addc_co_u32 %[mm], vcc, %[mm], %[mm], vcc"
                    : [vn]"=v"(vnew), [mm]"+v"(mhi[xx])
                    : [vd]"v"(vdec), [vz]"v"(fzero)
                    : "vcc");
                v[xx]  = vnew;
                ii[xx] = __fadd_rn(idec, gg7[xx]);
            }
        }

        // pooled row (ybase + r - 1): OR of 4 neighbor masks + LUT + FC accumulate
        if (r > 0) {
            const int py = ybase + r - 1;
            const int jbase = c * 36 + py * 6;
            #pragma unroll
            for (int px = 0; px < 6; ++px) {
                const unsigned int pl = plo[px] | plo[px+1] | mlo[px] | mlo[px+1];
                const unsigned int ph = phi[px] | phi[px+1] | mhi[px] | mhi[px+1];
                float a = s_tab[0][pl & 255] + s_tab[1][(pl >> 8) & 255]
                        + s_tab[2][(pl >> 16) & 255] + s_tab[3][pl >> 24]
                        + s_tab[4][ph & 255] + s_tab[5][(ph >> 8) & 255]
                        + s_tab[6][(ph >> 16) & 255] + s_tab[7][ph >> 24];
                const int j = jbase + px;
                #pragma unroll
                for (int o = 0; o < 10; ++o)
                    outacc[o] = fmaf(s_fcw[o * 72 + j], a, outacc[o]);
            }
        }
        #pragma unroll
        for (int xx = 0; xx < 7; ++xx) { plo[xx] = mlo[xx]; phi[xx] = mhi[xx]; }
    }

    // reduce over 4 lanes (h then c), add bias response, store
    #pragma unroll
    for (int o = 0; o < 10; ++o) {
        float t1  = outacc[o] + __shfl_xor(outacc[o], 1);
        float tot = t1 + __shfl_xor(t1, 2);
        tot = fmaf(cbsum, s_fcb[o], tot);
        if ((gt & 3) == 0) out[b * 10 + o] = tot;
    }
}

extern "C" void kernel_launch(void* const* d_in, const int* in_sizes, int n_in,
                              void* d_out, int out_size, void* d_ws, size_t ws_size,
                              hipStream_t stream) {
    const float* x      = (const float*)d_in[0];
    const float* conv_w = (const float*)d_in[1];
    const float* conv_b = (const float*)d_in[2];
    const float* fc_w   = (const float*)d_in[3];
    const float* fc_b   = (const float*)d_in[4];
    const int*   nsteps = (const int*)d_in[5];
    float* outp = (float*)d_out;

    const int B = in_sizes[0] / 100;
    const int total = 4 * B;   // 2 row-halves x 2 channels per batch
    const int block = 256;
    const int grid = (total + block - 1) / block;
    snn_fused<<<grid, block, 0, stream>>>(x, conv_w, conv_b, fc_w, fc_b, nsteps, outp, B);
}

// Round 6
// 83.297 us; speedup vs baseline: 3.3521x; 1.0930x over previous
//
#include <hip/hip_runtime.h>

#define TMAX 64

__global__ __launch_bounds__(256) void snn_fused(
    const float* __restrict__ x,       // [B,1,10,10]
    const float* __restrict__ conv_w,  // [2,1,4,4]
    const float* __restrict__ conv_b,  // [2]
    const float* __restrict__ fc_w,    // [10,72]
    const float* __restrict__ fc_b,    // [10]
    const int*   __restrict__ nsteps,  // scalar
    float*       __restrict__ out,     // [B,10]
    int B)
{
    __shared__ double d_F[TMAX];       // F(m) = 0.9^m - 0.8^m  (double)
    __shared__ float  s_r[TMAX];       // r_s = G(T-1-s)  (time-indexed)
    __shared__ float  s_rb[TMAX];      // bit-position -> r  (addc bit order)
    __shared__ float  s_tab[8][256];   // byte tables over s_rb
    __shared__ float  s_fcw[720];
    __shared__ float  s_fcb[16];
    __shared__ float  s_cb;            // C_b = sum_{m<T} F(m)

    const int tid = threadIdx.x;
    int T = nsteps[0];
    if (T > TMAX) T = TMAX;
    if (T < 0) T = 0;
    const int tlo = T < 32 ? T : 32;
    const int thi = T > 32 ? (T - 32) : 0;

    // --- setup: F(m) in double ---
    if (tid < TMAX) {
        double p9 = 1.0, p8 = 1.0;
        for (int k = 0; k < tid; ++k) { p9 *= 0.9; p8 *= 0.8; }
        d_F[tid] = p9 - p8;
    }
    for (int idx = tid; idx < 720; idx += 256) s_fcw[idx] = fc_w[idx];
    if (tid < 10) s_fcb[tid] = fc_b[tid];
    __syncthreads();

    // --- r_s = G(T-1-s), double accumulate ---
    if (tid < TMAX) {
        double r = 0.0;
        if (tid < T) {
            const int n = T - 1 - tid;
            for (int u = 0; u <= n; ++u) r += d_F[n - u] * d_F[u];
        }
        s_r[tid] = (float)r;
    }
    if (tid == 0) {
        double cb = 0.0;
        for (int m = 0; m < T; ++m) cb += d_F[m];
        s_cb = (float)cb;
    }
    __syncthreads();

    // --- bit-position -> r map (m = 2m + sp ordering) ---
    if (tid < 32) {
        s_rb[tid] = (tid < tlo) ? s_r[tlo - 1 - tid] : 0.f;
    } else if (tid < 64) {
        const int p = tid - 32;
        s_rb[tid] = (p < thi) ? s_r[tlo + thi - 1 - p] : 0.f;
    }
    __syncthreads();

    // --- byte lookup tables ---
    {
        const int v8 = tid; // 0..255
        #pragma unroll
        for (int k = 0; k < 8; ++k) {
            float ssum = 0.f;
            #pragma unroll
            for (int bb = 0; bb < 8; ++bb)
                if ((v8 >> bb) & 1) ssum += s_rb[k * 8 + bb];
            s_tab[k][v8] = ssum;
        }
    }
    __syncthreads();

    const float cbsum = s_cb;

    // lane mapping: 16 lanes per batch: sub = c*8 + y; y==7 lanes pad (clamp to row 6)
    const int gt  = blockIdx.x * 256 + tid;
    const int sub = gt & 15;
    const int b   = gt >> 4;
    const int c   = sub >> 3;
    const int y   = sub & 7;
    const int ysim = (y < 6) ? y : 6;
    if (b >= B) return;

    const float* xb = x + b * 100;
    const float cbias = conv_b[c];

    // ---- conv for row ysim: exact (ky asc, kx asc) sequential order, then +bias ----
    float gg7[7];
    #pragma unroll
    for (int xx = 0; xx < 7; ++xx) gg7[xx] = 0.f;
    {
        float wc[16];
        const float4* wq = reinterpret_cast<const float4*>(conv_w + c * 16);
        #pragma unroll
        for (int k = 0; k < 4; ++k) {
            float4 t = wq[k];
            wc[4*k+0] = t.x; wc[4*k+1] = t.y; wc[4*k+2] = t.z; wc[4*k+3] = t.w;
        }
        #pragma unroll
        for (int ky = 0; ky < 4; ++ky) {
            float xrow[10];
            const float2* q = reinterpret_cast<const float2*>(xb + (ysim + ky) * 10);
            #pragma unroll
            for (int k = 0; k < 5; ++k) { float2 t = q[k]; xrow[2*k] = t.x; xrow[2*k+1] = t.y; }
            #pragma unroll
            for (int xx = 0; xx < 7; ++xx) {
                float a = gg7[xx];
                #pragma unroll
                for (int kx = 0; kx < 4; ++kx)
                    a = __fadd_rn(a, __fmul_rn(wc[ky*4 + kx], xrow[xx + kx]));
                gg7[xx] = a;
            }
        }
    }
    #pragma unroll
    for (int xx = 0; xx < 7; ++xx) gg7[xx] = __fadd_rn(gg7[xx], cbias);

    // ---- LIF sim: exact reference fp32 arithmetic; spike bits via m = 2m + sp ----
    float v[7], ii[7];
    unsigned int mlo[7], mhi[7];
    float fzero = 0.0f;
    #pragma unroll
    for (int xx = 0; xx < 7; ++xx) { v[xx] = 0.f; ii[xx] = 0.f; mlo[xx] = 0u; mhi[xx] = 0u; }

    #pragma unroll 4
    for (int t = 0; t < tlo; ++t) {
        #pragma unroll
        for (int xx = 0; xx < 7; ++xx) {
            const float imv  = __fsub_rn(ii[xx], v[xx]);
            const float vdec = __fadd_rn(v[xx], __fmul_rn(0.1f, imv));
            const float idec = __fsub_rn(ii[xx], __fmul_rn(0.2f, ii[xx]));
            float vnew;
            asm("v_cmp_lt_f32 vcc, 1.0, %[vd]\n\t"
                "v_cndmask_b32 %[vn], %[vd], %[vz], vcc\n\t"
                "v_addc_co_u32 %[mm], vcc, %[mm], %[mm], vcc"
                : [vn]"=v"(vnew), [mm]"+v"(mlo[xx])
                : [vd]"v"(vdec), [vz]"v"(fzero)
                : "vcc");
            v[xx]  = vnew;
            ii[xx] = __fadd_rn(idec, gg7[xx]);
        }
    }
    #pragma unroll 4
    for (int t = 0; t < thi; ++t) {
        #pragma unroll
        for (int xx = 0; xx < 7; ++xx) {
            const float imv  = __fsub_rn(ii[xx], v[xx]);
            const float vdec = __fadd_rn(v[xx], __fmul_rn(0.1f, imv));
            const float idec = __fsub_rn(ii[xx], __fmul_rn(0.2f, ii[xx]));
            float vnew;
            asm("v_cmp_lt_f32 vcc, 1.0, %[vd]\n\t"
                "v_cndmask_b32 %[vn], %[vd], %[vz], vcc\n\t"
                "v_addc_co_u32 %[mm], vcc, %[mm], %[mm], vcc"
                : [vn]"=v"(vnew), [mm]"+v"(mhi[xx])
                : [vd]"v"(vdec), [vz]"v"(fzero)
                : "vcc");
            v[xx]  = vnew;
            ii[xx] = __fadd_rn(idec, gg7[xx]);
        }
    }

    // ---- neighbor-row masks via shfl (lane y+1, same c) ----
    unsigned int nlo[7], nhi[7];
    #pragma unroll
    for (int xx = 0; xx < 7; ++xx) {
        nlo[xx] = __shfl_down(mlo[xx], 1);
        nhi[xx] = __shfl_down(mhi[xx], 1);
    }

    // ---- pooled row y (if y<6): OR of 4 masks + LUT + FC partials ----
    float outacc[10];
    #pragma unroll
    for (int o = 0; o < 10; ++o) outacc[o] = 0.f;

    if (y < 6) {
        const int jbase = c * 36 + y * 6;
        #pragma unroll
        for (int px = 0; px < 6; ++px) {
            const unsigned int pl = mlo[px] | mlo[px+1] | nlo[px] | nlo[px+1];
            const unsigned int ph = mhi[px] | mhi[px+1] | nhi[px] | nhi[px+1];
            float a = s_tab[0][pl & 255] + s_tab[1][(pl >> 8) & 255]
                    + s_tab[2][(pl >> 16) & 255] + s_tab[3][pl >> 24]
                    + s_tab[4][ph & 255] + s_tab[5][(ph >> 8) & 255]
                    + s_tab[6][(ph >> 16) & 255] + s_tab[7][ph >> 24];
            const int j = jbase + px;
            #pragma unroll
            for (int o = 0; o < 10; ++o)
                outacc[o] = fmaf(s_fcw[o * 72 + j], a, outacc[o]);
        }
    }

    // ---- reduce over the 16-lane group, add bias response, store ----
    #pragma unroll
    for (int o = 0; o < 10; ++o) {
        float t = outacc[o];
        t += __shfl_xor(t, 1);
        t += __shfl_xor(t, 2);
        t += __shfl_xor(t, 4);
        t += __shfl_xor(t, 8);
        if (sub == 0) out[b * 10 + o] = fmaf(cbsum, s_fcb[o], t);
    }
}

extern "C" void kernel_launch(void* const* d_in, const int* in_sizes, int n_in,
                              void* d_out, int out_size, void* d_ws, size_t ws_size,
                              hipStream_t stream) {
    const float* x      = (const float*)d_in[0];
    const float* conv_w = (const float*)d_in[1];
    const float* conv_b = (const float*)d_in[2];
    const float* fc_w   = (const float*)d_in[3];
    const float* fc_b   = (const float*)d_in[4];
    const int*   nsteps = (const int*)d_in[5];
    float* outp = (float*)d_out;

    const int B = in_sizes[0] / 100;
    const int total = 16 * B;   // lane = c*8 + y per batch
    const int block = 256;
    const int grid = (total + block - 1) / block;
    snn_fused<<<grid, block, 0, stream>>>(x, conv_w, conv_b, fc_w, fc_b, nsteps, outp, B);
}